// Round 5
// baseline (327.176 us; speedup 1.0000x reference)
//
#include <hip/hip_runtime.h>
#include <stdint.h>

#define NB 16
#define NC 256
#define NH 48
#define NW 160
#define HW (NH*NW)        // 7680
#define NP (NB*HW)        // 122880

static __device__ __forceinline__ unsigned short f2bf(float f){
  union { float f; uint32_t u; } v; v.f = f;
  uint32_t u = v.u;
  uint32_t r = (u + 0x7FFFu + ((u >> 16) & 1u)) >> 16;
  return (unsigned short)r;
}
static __device__ __forceinline__ float bf2f(unsigned short h){
  union { float f; uint32_t u; } v; v.u = ((uint32_t)h) << 16; return v.f;
}

// ---- KW: produce FRAGMENT-MAJOR weights so kb's A-loads are lane-contiguous.
__global__ __launch_bounds__(256) void kw_conv(const float* __restrict__ w_ext,
                                               const float* __restrict__ w_disp,
                                               unsigned short* __restrict__ WbF,
                                               unsigned short* __restrict__ WtapF){
  int d = blockIdx.x * 256 + threadIdx.x;
  if (blockIdx.x < 256){
    int j  = d & 7;
    int lane = (d >> 3) & 63;
    int mi = (d >> 9) & 3;
    int w  = (d >> 11) & 3;
    int ks = d >> 13;
    int m = w * 64 + mi * 16 + (lane & 15);
    int k = ks * 32 + (lane >> 4) * 8 + j;
    WbF[d] = f2bf(w_ext[m * 257 + 1 + k]);
  } else {
    int d2 = d - 65536;                 // 0..4095
    int j  = d2 & 7;
    int lane = (d2 >> 3) & 63;
    int ks = d2 >> 9;
    int tap = lane & 15;
    int k = ks * 32 + (lane >> 4) * 8 + j;
    WtapF[d2] = (tap < 9) ? f2bf(w_disp[k * 9 + tap]) : (unsigned short)0;
  }
}

// ---- KB: fused transpose-stage + GEMM, SINGLE-STAGE, dwordx2 staging.
//   U is stored PIXEL-MAJOR: U'[b*HW + p][o] (256 bf16 per row) so the
//   epilogue packs 4 consecutive-o values per lane into one 8-B store
//   (64 store instrs/block instead of 256) and kc reads 16-B-wide rows.
typedef __attribute__((ext_vector_type(8))) short bf16x8;
typedef __attribute__((ext_vector_type(4))) short bf16x4;
typedef __attribute__((ext_vector_type(4))) float f32x4;

__global__ __launch_bounds__(256, 2) void kb_gemm(
    const float* __restrict__ x,             // [NB][NC][HW] fp32
    const unsigned short* __restrict__ Wb,   // fragment-major, 65536 shorts
    const unsigned short* __restrict__ Wtap, // fragment-major, 4096 shorts
    unsigned short* __restrict__ U,          // [NB*HW][256] bf16 (pixel-major)
    float* __restrict__ T)                   // [9][NP] fp32
{
  // [ks][unit][(n15 + kq*16)*8 + j] : 8 * 4 * 512 shorts = 32 KB
  __shared__ __align__(16) unsigned short smem[8 * 2048];
  int bx = blockIdx.x;            // 1920 = 16 b * 120 nt
  int b  = bx / 120;
  int nt = bx - b * 120;
  int p0 = nt * 64;               // hw offset within image (64 | 7680)

  int tid  = threadIdx.x;
  int lane = tid & 63;
  int w    = tid >> 6;            // wave 0..3 ; wm = w (m-quarter of 64)
  int l15 = lane & 15;
  int lq  = lane >> 4;

  // ---- staging loads: issue ALL 32 dwordx2 before anything else ----------
  int q  = tid & 31;              // pixel pair: n = 2q, 2q+1
  int cg = tid >> 5;              // 0..7 : channels cg*32 .. cg*32+31 (= k-step)
  const float* xs = x + ((size_t)b * NC + (size_t)cg * 32) * HW + p0 + 2 * q;

  float2 v[32];
  #pragma unroll
  for (int i = 0; i < 32; ++i)
    v[i] = *(const float2*)(xs + (size_t)i * HW);

  // A fragments for ks=0 (L2-hot) issued after the x loads
  bf16x8 afA[4], afB[4];
  bf16x8 atA = {0,0,0,0,0,0,0,0}, atB = {0,0,0,0,0,0,0,0};
  #pragma unroll
  for (int mi = 0; mi < 4; ++mi)
    afA[mi] = *(const bf16x8*)(Wb + ((w * 4 + mi) << 9) + lane * 8);
  if (w == 0)
    atA = *(const bf16x8*)(Wtap + lane * 8);

  f32x4 zero = {0.f, 0.f, 0.f, 0.f};
  f32x4 acc[4][4];
  f32x4 acct[4];
  #pragma unroll
  for (int mi = 0; mi < 4; ++mi){
    acct[mi] = zero;
    #pragma unroll
    for (int ni = 0; ni < 4; ++ni) acc[mi][ni] = zero;
  }

  // ---- convert + LDS write, group-wise as loads arrive --------------------
  {
    int n0 = 2 * q;                         // even, n0 and n0+1 share a unit
    unsigned short* sw0 = smem + cg * 2048 + (n0 >> 4) * 512;
    int n15a = n0 & 15;
    #pragma unroll
    for (int g = 0; g < 4; ++g){
      unsigned short ha[8], hb[8];
      #pragma unroll
      for (int j = 0; j < 8; ++j){
        ha[j] = f2bf(v[8 * g + j].x);
        hb[j] = f2bf(v[8 * g + j].y);
      }
      *(bf16x8*)(sw0 + (n15a     + g * 16) * 8) = *(bf16x8*)ha;
      *(bf16x8*)(sw0 + (n15a + 1 + g * 16) * 8) = *(bf16x8*)hb;
    }
  }
  __syncthreads();

  // ---- compute phase: 8 steps, no barriers, depth-1 A prefetch ------------
#define KB_STEP(T_, AFC, AFN, ATC, ATN)                                       \
  {                                                                           \
    constexpr int t_ = (T_);                                                  \
    if (t_ + 1 < 8) {                                                         \
      _Pragma("unroll")                                                       \
      for (int mi = 0; mi < 4; ++mi)                                          \
        AFN[mi] = *(const bf16x8*)(Wb + (((t_ + 1) * 16 + w * 4 + mi) << 9)   \
                                   + lane * 8);                               \
      if (w == 0)                                                             \
        ATN = *(const bf16x8*)(Wtap + ((t_ + 1) << 9) + lane * 8);            \
    }                                                                         \
    bf16x8 bg[4];                                                             \
    _Pragma("unroll")                                                         \
    for (int ni = 0; ni < 4; ++ni)                                            \
      bg[ni] = *(const bf16x8*)(smem + t_ * 2048 + ni * 512 + lane * 8);      \
    _Pragma("unroll")                                                         \
    for (int mi = 0; mi < 4; ++mi)                                            \
      _Pragma("unroll")                                                       \
      for (int ni = 0; ni < 4; ++ni)                                          \
        acc[mi][ni] = __builtin_amdgcn_mfma_f32_16x16x32_bf16(AFC[mi], bg[ni],\
                                                      acc[mi][ni], 0, 0, 0);  \
    if (w == 0) {                                                             \
      _Pragma("unroll")                                                       \
      for (int ni = 0; ni < 4; ++ni)                                          \
        acct[ni] = __builtin_amdgcn_mfma_f32_16x16x32_bf16(ATC, bg[ni],       \
                                                       acct[ni], 0, 0, 0);    \
    }                                                                         \
  }

  KB_STEP(0, afA, afB, atA, atB)
  KB_STEP(1, afB, afA, atB, atA)
  KB_STEP(2, afA, afB, atA, atB)
  KB_STEP(3, afB, afA, atB, atA)
  KB_STEP(4, afA, afB, atA, atB)
  KB_STEP(5, afB, afA, atB, atA)
  KB_STEP(6, afA, afB, atA, atB)
  KB_STEP(7, afB, afA, atB, atA)
#undef KB_STEP

  // epilogue U (pixel-major): lane packs its 4 consecutive-o values (r=0..3)
  // into one 8-B store at row (p0+n), col o.  64 store instrs/block.
  #pragma unroll
  for (int mi = 0; mi < 4; ++mi){
    int o = w * 64 + mi * 16 + lq * 4;
    #pragma unroll
    for (int ni = 0; ni < 4; ++ni){
      int n = ni * 16 + l15;
      unsigned short h[4];
      #pragma unroll
      for (int r = 0; r < 4; ++r) h[r] = f2bf(acc[mi][ni][r]);
      *(bf16x4*)(U + ((size_t)b * HW + p0 + n) * 256 + o) = *(bf16x4*)h;
    }
  }
  // epilogue T (wave 0): row = lq*4+r = tap index, keep rows 0..8
  if (w == 0){
    #pragma unroll
    for (int ni = 0; ni < 4; ++ni){
      int n = ni * 16 + l15;
      #pragma unroll
      for (int r = 0; r < 4; ++r){
        int k = lq * 4 + r;
        if (k < 9)
          T[(size_t)k * NP + (size_t)b * HW + p0 + n] = acct[ni][r];
      }
    }
  }
}

// ---- KP: per-pixel grid params (wy, dlerp, off0, off1) ----------------------
__global__ __launch_bounds__(256) void kp_grid(
    const float* __restrict__ P2, const float* __restrict__ b_disp,
    const float* __restrict__ T, float4* __restrict__ pre)
{
  int p = blockIdx.x * 256 + threadIdx.x;   // 0..122879
  int b  = p / HW;
  int hw = p - b * HW;
  int y  = hw / NW;
  int xx = hw - y * NW;

  float d = 0.f;
  #pragma unroll
  for (int ky = 0; ky < 3; ++ky){
    int yy2 = y + ky - 1;
    if (yy2 < 0 || yy2 >= NH) continue;
    #pragma unroll
    for (int kx = 0; kx < 3; ++kx){
      int xx2 = xx + kx - 1;
      if (xx2 < 0 || xx2 >= NW) continue;
      d += T[(size_t)(ky * 3 + kx) * NP + b * HW + yy2 * NW + xx2];
    }
  }
  float th = tanhf(d + b_disp[0]);

  float fy = P2[b * 12 + 5] * 0.0625f;
  float cy = P2[b * 12 + 6] * 0.0625f;
  float Ty = P2[b * 12 + 7] * 0.0625f;

  float ysb   = fmaxf(1.535f * ((float)y - cy) / 1.765f, 0.f) * (1.f / 24.f);
  float ybase = -1.f + (float)y * (2.f / 47.f);
  float gy = ybase + ysb + 0.1f * th;
  float iy = fminf(fmaxf((gy + 1.f) * 0.5f * 47.f, 0.f), 47.f);
  float fiy0 = floorf(iy);
  float wy = iy - fiy0;
  int iy0 = (int)fiy0;
  int iy1 = min(iy0 + 1, 47);

  float inv_den = 1.f / (fabsf(fy * 1.65f + Ty) + 1e-10f);
  float dr0 = fmaxf(fy * 0.54f * ((float)iy0 - cy) * inv_den, 0.f);
  float dr1 = fmaxf(fy * 0.54f * ((float)iy1 - cy) * inv_den, 0.f);
  float dlerp = (1.f - wy) * dr0 + wy * dr1;

  float4 pr;
  pr.x = wy; pr.y = dlerp;
  pr.z = __int_as_float(iy0 * NW + xx);
  pr.w = __int_as_float(iy1 * NW + xx);
  pre[p] = pr;
}

// ---- KC: lerp + matvec-residual ReLU; U rows read 16-B wide ----------------
__global__ __launch_bounds__(256) void kc_epilogue(
    const float* __restrict__ x, const float* __restrict__ w_ext,
    const float* __restrict__ b_ext, const float* __restrict__ alpha,
    const unsigned short* __restrict__ U, const float4* __restrict__ pre,
    float* __restrict__ out)
{
  int bx = blockIdx.x;            // 3840 = 480 ptile * 8 cg
  int ptile = bx >> 3;
  int cg    = bx & 7;
  int p = ptile * 256 + threadIdx.x;
  int b  = p / HW;
  int hw = p - b * HW;

  float4 pr = pre[p];
  float wy    = pr.x;
  float dlerp = pr.y;
  int off0 = __float_as_int(pr.z);
  int off1 = __float_as_int(pr.w);
  float w1 = 1.f - wy;
  float al = alpha[0];

  int o0 = cg * 32;
  const unsigned short* U0 = U + ((size_t)b * HW + off0) * 256 + o0;
  const unsigned short* U1 = U + ((size_t)b * HW + off1) * 256 + o0;
  bf16x8 ua[4], ub[4];
  #pragma unroll
  for (int i = 0; i < 4; ++i){
    ua[i] = *(const bf16x8*)(U0 + i * 8);
    ub[i] = *(const bf16x8*)(U1 + i * 8);
  }

  size_t base0 = (size_t)(b * NC) * HW;
  const float* xb = x + base0 + hw;
  float* ob = out + base0 + hw;

  #pragma unroll
  for (int i = 0; i < 4; ++i){
    #pragma unroll
    for (int j = 0; j < 8; ++j){
      int o = o0 + i * 8 + j;
      float u0 = bf2f((unsigned short)ua[i][j]);
      float u1 = bf2f((unsigned short)ub[i][j]);
      float val = w1 * u0 + wy * u1 + w_ext[o * 257] * dlerp + b_ext[o];
      float r = xb[(size_t)o * HW] + al * val;
      ob[(size_t)o * HW] = fmaxf(r, 0.f);
    }
  }
}

// ---------------------------------------------------------------------------
extern "C" void kernel_launch(void* const* d_in, const int* in_sizes, int n_in,
                              void* d_out, int out_size, void* d_ws, size_t ws_size,
                              hipStream_t stream) {
  const float* features = (const float*)d_in[0];
  const float* P2       = (const float*)d_in[1];
  const float* w_disp   = (const float*)d_in[2];
  const float* b_disp   = (const float*)d_in[3];
  const float* w_ext    = (const float*)d_in[4];
  const float* b_ext    = (const float*)d_in[5];
  const float* alpha    = (const float*)d_in[6];
  float* out = (float*)d_out;

  char* ws = (char*)d_ws;
  const size_t U_bytes   = (size_t)NP * 256 * 2;    // 62,914,560
  const size_t T_bytes   = (size_t)9 * NP * 4;      //  4,423,680
  const size_t pre_bytes = (size_t)NP * 16;         //  1,966,080
  unsigned short* U    = (unsigned short*)ws;
  float*          T    = (float*)(ws + U_bytes);
  float4*         pre  = (float4*)(ws + U_bytes + T_bytes);
  unsigned short* Wb   = (unsigned short*)(ws + U_bytes + T_bytes + pre_bytes);
  unsigned short* Wtap = Wb + 256 * 256;

  hipLaunchKernelGGL(kw_conv,     dim3(272),  dim3(256), 0, stream, w_ext, w_disp, Wb, Wtap);
  hipLaunchKernelGGL(kb_gemm,     dim3(1920), dim3(256), 0, stream, features, Wb, Wtap, U, T);
  hipLaunchKernelGGL(kp_grid,     dim3(480),  dim3(256), 0, stream, P2, b_disp, T, pre);
  hipLaunchKernelGGL(kc_epilogue, dim3(3840), dim3(256), 0, stream,
                     features, w_ext, b_ext, alpha, U, pre, out);
}

// Round 6
// 318.961 us; speedup vs baseline: 1.0258x; 1.0258x over previous
//
#include <hip/hip_runtime.h>
#include <stdint.h>

#define NB 16
#define NC 256
#define NH 48
#define NW 160
#define HW (NH*NW)        // 7680
#define NP (NB*HW)        // 122880

static __device__ __forceinline__ unsigned short f2bf(float f){
  union { float f; uint32_t u; } v; v.f = f;
  uint32_t u = v.u;
  uint32_t r = (u + 0x7FFFu + ((u >> 16) & 1u)) >> 16;
  return (unsigned short)r;
}
static __device__ __forceinline__ float bf2f(unsigned short h){
  union { float f; uint32_t u; } v; v.u = ((uint32_t)h) << 16; return v.f;
}

// ---- KW: produce FRAGMENT-MAJOR weights so kb's A-loads are lane-contiguous.
__global__ __launch_bounds__(256) void kw_conv(const float* __restrict__ w_ext,
                                               const float* __restrict__ w_disp,
                                               unsigned short* __restrict__ WbF,
                                               unsigned short* __restrict__ WtapF){
  int d = blockIdx.x * 256 + threadIdx.x;
  if (blockIdx.x < 256){
    int j  = d & 7;
    int lane = (d >> 3) & 63;
    int mi = (d >> 9) & 3;
    int w  = (d >> 11) & 3;
    int ks = d >> 13;
    int m = w * 64 + mi * 16 + (lane & 15);
    int k = ks * 32 + (lane >> 4) * 8 + j;
    WbF[d] = f2bf(w_ext[m * 257 + 1 + k]);
  } else {
    int d2 = d - 65536;                 // 0..4095
    int j  = d2 & 7;
    int lane = (d2 >> 3) & 63;
    int ks = d2 >> 9;
    int tap = lane & 15;
    int k = ks * 32 + (lane >> 4) * 8 + j;
    WtapF[d2] = (tap < 9) ? f2bf(w_disp[k * 9 + tap]) : (unsigned short)0;
  }
}

// ---- KB: fused transpose-stage + GEMM, SINGLE-STAGE, ASM-pinned depth-32.
//   32 global_load_dwordx2 issued via inline asm (compiler cannot
//   re-serialize), drained with counted vmcnt(24/16/8/5) around 4 convert
//   groups; A-prologue loads stay in flight across a raw s_barrier.
typedef __attribute__((ext_vector_type(8))) short bf16x8;
typedef __attribute__((ext_vector_type(4))) float f32x4;

__global__ __launch_bounds__(256, 3) void kb_gemm(
    const float* __restrict__ x,             // [NB][NC][HW] fp32
    const unsigned short* __restrict__ Wb,   // fragment-major, 65536 shorts
    const unsigned short* __restrict__ Wtap, // fragment-major, 4096 shorts
    unsigned short* __restrict__ U,          // [NB*NC][HW] bf16 (channel-major)
    float* __restrict__ T)                   // [9][NP] fp32
{
  // [ks][unit][(n15 + kq*16)*8 + j] : 8 * 4 * 512 shorts = 32 KB
  __shared__ __align__(16) unsigned short smem[8 * 2048];
  int bx = blockIdx.x;            // 1920 = 16 b * 120 nt
  int b  = bx / 120;
  int nt = bx - b * 120;
  int p0 = nt * 64;               // hw offset within image (64 | 7680)

  int tid  = threadIdx.x;
  int lane = tid & 63;
  int w    = tid >> 6;            // wave 0..3 ; wm = w (m-quarter of 64)
  int l15 = lane & 15;
  int lq  = lane >> 4;

  // staging role: thread = (pixel pair q, 32-ch group cg)
  int q  = tid & 31;              // pixel pair: n = 2q, 2q+1
  int cg = tid >> 5;              // 0..7 : channels cg*32..cg*32+31 (= k-step)
  const float* xb_u = x + (size_t)b * NC * HW + p0;   // wave-uniform base
  uint32_t voff0 = ((uint32_t)cg * 32u * (uint32_t)HW + 2u * (uint32_t)q) * 4u;

  // ---- issue ALL 32 staging loads via asm (depth-32, pinned) --------------
  float2 v[32];
#define GL(i) asm volatile("global_load_dwordx2 %0, %1, %2"                   \
    : "=v"(v[i])                                                              \
    : "v"(voff0 + (uint32_t)((i) * HW * 4)), "s"(xb_u) : "memory")
  GL(0); GL(1); GL(2); GL(3); GL(4); GL(5); GL(6); GL(7);
  GL(8); GL(9); GL(10); GL(11); GL(12); GL(13); GL(14); GL(15);
  GL(16); GL(17); GL(18); GL(19); GL(20); GL(21); GL(22); GL(23);
  GL(24); GL(25); GL(26); GL(27); GL(28); GL(29); GL(30); GL(31);
#undef GL

  // A-prologue (ks=0): issued after x loads; 5 loads/wave (atA unconditional
  // so every wave carries exactly 5 — keeps vmcnt arithmetic wave-uniform).
  bf16x8 afA[4], afB[4];
  bf16x8 atA, atB = {0,0,0,0,0,0,0,0};
  #pragma unroll
  for (int mi = 0; mi < 4; ++mi)
    afA[mi] = *(const bf16x8*)(Wb + ((w * 4 + mi) << 9) + lane * 8);
  atA = *(const bf16x8*)(Wtap + lane * 8);

  f32x4 zero = {0.f, 0.f, 0.f, 0.f};
  f32x4 acc[4][4];
  f32x4 acct[4];
  #pragma unroll
  for (int mi = 0; mi < 4; ++mi){
    acct[mi] = zero;
    #pragma unroll
    for (int ni = 0; ni < 4; ++ni) acc[mi][ni] = zero;
  }

  // ---- counted drains + convert groups ------------------------------------
  // group g converts v[8g..8g+7] (k-quad kq=g) into LDS.  x-done = 32 - N
  // independent of extra in-flight compiler loads (in-order vmcnt).
  int n0 = 2 * q;
  unsigned short* sw0 = smem + cg * 2048 + (n0 >> 4) * 512;
  int n15a = n0 & 15;
#define CVT_GROUP(g)                                                          \
  { unsigned short ha[8], hb[8];                                              \
    _Pragma("unroll")                                                         \
    for (int j = 0; j < 8; ++j){                                              \
      ha[j] = f2bf(v[8 * (g) + j].x);                                         \
      hb[j] = f2bf(v[8 * (g) + j].y);                                         \
    }                                                                         \
    *(bf16x8*)(sw0 + (n15a     + (g) * 16) * 8) = *(bf16x8*)ha;               \
    *(bf16x8*)(sw0 + (n15a + 1 + (g) * 16) * 8) = *(bf16x8*)hb;               \
  }

  asm volatile("s_waitcnt vmcnt(24)" ::: "memory");
  __builtin_amdgcn_sched_barrier(0);
  CVT_GROUP(0)
  asm volatile("s_waitcnt vmcnt(16)" ::: "memory");
  __builtin_amdgcn_sched_barrier(0);
  CVT_GROUP(1)
  asm volatile("s_waitcnt vmcnt(8)" ::: "memory");
  __builtin_amdgcn_sched_barrier(0);
  CVT_GROUP(2)
  asm volatile("s_waitcnt vmcnt(5)" ::: "memory");   // all x done; A stays in flight
  __builtin_amdgcn_sched_barrier(0);
  CVT_GROUP(3)
#undef CVT_GROUP

  asm volatile("s_waitcnt lgkmcnt(0)" ::: "memory"); // LDS writes visible
  __builtin_amdgcn_sched_barrier(0);
  __builtin_amdgcn_s_barrier();
  __builtin_amdgcn_sched_barrier(0);

  // ---- compute phase: 8 steps, no barriers, depth-1 A prefetch ------------
#define KB_STEP(T_, AFC, AFN, ATC, ATN)                                       \
  {                                                                           \
    constexpr int t_ = (T_);                                                  \
    if (t_ + 1 < 8) {                                                         \
      _Pragma("unroll")                                                       \
      for (int mi = 0; mi < 4; ++mi)                                          \
        AFN[mi] = *(const bf16x8*)(Wb + (((t_ + 1) * 16 + w * 4 + mi) << 9)   \
                                   + lane * 8);                               \
      if (w == 0)                                                             \
        ATN = *(const bf16x8*)(Wtap + ((t_ + 1) << 9) + lane * 8);            \
    }                                                                         \
    bf16x8 bg[4];                                                             \
    _Pragma("unroll")                                                         \
    for (int ni = 0; ni < 4; ++ni)                                            \
      bg[ni] = *(const bf16x8*)(smem + t_ * 2048 + ni * 512 + lane * 8);      \
    _Pragma("unroll")                                                         \
    for (int mi = 0; mi < 4; ++mi)                                            \
      _Pragma("unroll")                                                       \
      for (int ni = 0; ni < 4; ++ni)                                          \
        acc[mi][ni] = __builtin_amdgcn_mfma_f32_16x16x32_bf16(AFC[mi], bg[ni],\
                                                      acc[mi][ni], 0, 0, 0);  \
    if (w == 0) {                                                             \
      _Pragma("unroll")                                                       \
      for (int ni = 0; ni < 4; ++ni)                                          \
        acct[ni] = __builtin_amdgcn_mfma_f32_16x16x32_bf16(ATC, bg[ni],       \
                                                       acct[ni], 0, 0, 0);    \
    }                                                                         \
  }

  KB_STEP(0, afA, afB, atA, atB)
  KB_STEP(1, afB, afA, atB, atA)
  KB_STEP(2, afA, afB, atA, atB)
  KB_STEP(3, afB, afA, atB, atA)
  KB_STEP(4, afA, afB, atA, atB)
  KB_STEP(5, afB, afA, atB, atA)
  KB_STEP(6, afA, afB, atA, atB)
  KB_STEP(7, afB, afA, atB, atA)
#undef KB_STEP

  // epilogue U (channel-major): C/D layout col=lane&15 (n), row=lq*4+r (m)
  #pragma unroll
  for (int mi = 0; mi < 4; ++mi){
    #pragma unroll
    for (int ni = 0; ni < 4; ++ni){
      int o = w * 64 + mi * 16 + lq * 4;
      int n = ni * 16 + l15;
      size_t base = ((size_t)(b * NC + o)) * HW + p0 + n;
      #pragma unroll
      for (int r = 0; r < 4; ++r)
        U[base + (size_t)r * HW] = f2bf(acc[mi][ni][r]);
    }
  }
  // epilogue T (wave 0): row = lq*4+r = tap index, keep rows 0..8
  if (w == 0){
    #pragma unroll
    for (int ni = 0; ni < 4; ++ni){
      int n = ni * 16 + l15;
      #pragma unroll
      for (int r = 0; r < 4; ++r){
        int k = lq * 4 + r;
        if (k < 9)
          T[(size_t)k * NP + (size_t)b * HW + p0 + n] = acct[ni][r];
      }
    }
  }
}

// ---- KP: per-pixel grid params (wy, dlerp, off0, off1) ----------------------
__global__ __launch_bounds__(256) void kp_grid(
    const float* __restrict__ P2, const float* __restrict__ b_disp,
    const float* __restrict__ T, float4* __restrict__ pre)
{
  int p = blockIdx.x * 256 + threadIdx.x;   // 0..122879
  int b  = p / HW;
  int hw = p - b * HW;
  int y  = hw / NW;
  int xx = hw - y * NW;

  float d = 0.f;
  #pragma unroll
  for (int ky = 0; ky < 3; ++ky){
    int yy2 = y + ky - 1;
    if (yy2 < 0 || yy2 >= NH) continue;
    #pragma unroll
    for (int kx = 0; kx < 3; ++kx){
      int xx2 = xx + kx - 1;
      if (xx2 < 0 || xx2 >= NW) continue;
      d += T[(size_t)(ky * 3 + kx) * NP + b * HW + yy2 * NW + xx2];
    }
  }
  float th = tanhf(d + b_disp[0]);

  float fy = P2[b * 12 + 5] * 0.0625f;
  float cy = P2[b * 12 + 6] * 0.0625f;
  float Ty = P2[b * 12 + 7] * 0.0625f;

  float ysb   = fmaxf(1.535f * ((float)y - cy) / 1.765f, 0.f) * (1.f / 24.f);
  float ybase = -1.f + (float)y * (2.f / 47.f);
  float gy = ybase + ysb + 0.1f * th;
  float iy = fminf(fmaxf((gy + 1.f) * 0.5f * 47.f, 0.f), 47.f);
  float fiy0 = floorf(iy);
  float wy = iy - fiy0;
  int iy0 = (int)fiy0;
  int iy1 = min(iy0 + 1, 47);

  float inv_den = 1.f / (fabsf(fy * 1.65f + Ty) + 1e-10f);
  float dr0 = fmaxf(fy * 0.54f * ((float)iy0 - cy) * inv_den, 0.f);
  float dr1 = fmaxf(fy * 0.54f * ((float)iy1 - cy) * inv_den, 0.f);
  float dlerp = (1.f - wy) * dr0 + wy * dr1;

  float4 pr;
  pr.x = wy; pr.y = dlerp;
  pr.z = __int_as_float(iy0 * NW + xx);
  pr.w = __int_as_float(iy1 * NW + xx);
  pre[p] = pr;
}

// ---- KC: lerp + matvec-residual ReLU, split over 8 channel groups ----------
__global__ __launch_bounds__(256) void kc_epilogue(
    const float* __restrict__ x, const float* __restrict__ w_ext,
    const float* __restrict__ b_ext, const float* __restrict__ alpha,
    const unsigned short* __restrict__ U, const float4* __restrict__ pre,
    float* __restrict__ out)
{
  int bx = blockIdx.x;            // 3840 = 480 ptile * 8 cg
  int ptile = bx >> 3;
  int cg    = bx & 7;
  int p = ptile * 256 + threadIdx.x;
  int b  = p / HW;
  int hw = p - b * HW;

  float4 pr = pre[p];
  float wy    = pr.x;
  float dlerp = pr.y;
  int off0 = __float_as_int(pr.z);
  int off1 = __float_as_int(pr.w);
  float w1 = 1.f - wy;
  float al = alpha[0];

  size_t base0 = (size_t)(b * NC) * HW;
  const unsigned short* Ub = U + base0;
  const float* xb = x + base0 + hw;
  float* ob = out + base0 + hw;

  int o0 = cg * 32;
  #pragma unroll 4
  for (int o = o0; o < o0 + 32; ++o){
    float u0 = bf2f(Ub[(size_t)o * HW + off0]);
    float u1 = bf2f(Ub[(size_t)o * HW + off1]);
    float val = w1 * u0 + wy * u1 + w_ext[o * 257] * dlerp + b_ext[o];
    float r = xb[(size_t)o * HW] + al * val;
    ob[(size_t)o * HW] = fmaxf(r, 0.f);
  }
}

// ---------------------------------------------------------------------------
extern "C" void kernel_launch(void* const* d_in, const int* in_sizes, int n_in,
                              void* d_out, int out_size, void* d_ws, size_t ws_size,
                              hipStream_t stream) {
  const float* features = (const float*)d_in[0];
  const float* P2       = (const float*)d_in[1];
  const float* w_disp   = (const float*)d_in[2];
  const float* b_disp   = (const float*)d_in[3];
  const float* w_ext    = (const float*)d_in[4];
  const float* b_ext    = (const float*)d_in[5];
  const float* alpha    = (const float*)d_in[6];
  float* out = (float*)d_out;

  char* ws = (char*)d_ws;
  const size_t U_bytes   = (size_t)NP * 256 * 2;    // 62,914,560
  const size_t T_bytes   = (size_t)9 * NP * 4;      //  4,423,680
  const size_t pre_bytes = (size_t)NP * 16;         //  1,966,080
  unsigned short* U    = (unsigned short*)ws;
  float*          T    = (float*)(ws + U_bytes);
  float4*         pre  = (float4*)(ws + U_bytes + T_bytes);
  unsigned short* Wb   = (unsigned short*)(ws + U_bytes + T_bytes + pre_bytes);
  unsigned short* Wtap = Wb + 256 * 256;

  hipLaunchKernelGGL(kw_conv,     dim3(272),  dim3(256), 0, stream, w_ext, w_disp, Wb, Wtap);
  hipLaunchKernelGGL(kb_gemm,     dim3(1920), dim3(256), 0, stream, features, Wb, Wtap, U, T);
  hipLaunchKernelGGL(kp_grid,     dim3(480),  dim3(256), 0, stream, P2, b_disp, T, pre);
  hipLaunchKernelGGL(kc_epilogue, dim3(3840), dim3(256), 0, stream,
                     features, w_ext, b_ext, alpha, U, pre, out);
}

// Round 7
// 292.176 us; speedup vs baseline: 1.1198x; 1.0917x over previous
//
#include <hip/hip_runtime.h>
#include <stdint.h>

#define NB 16
#define NC 256
#define NH 48
#define NW 160
#define HW (NH*NW)        // 7680
#define NP (NB*HW)        // 122880

static __device__ __forceinline__ unsigned short f2bf(float f){
  union { float f; uint32_t u; } v; v.f = f;
  uint32_t u = v.u;
  uint32_t r = (u + 0x7FFFu + ((u >> 16) & 1u)) >> 16;
  return (unsigned short)r;
}
static __device__ __forceinline__ float bf2f(unsigned short h){
  union { float f; uint32_t u; } v; v.u = ((uint32_t)h) << 16; return v.f;
}

// ---- KW: produce FRAGMENT-MAJOR weights so kb's A-loads are lane-contiguous.
__global__ __launch_bounds__(256) void kw_conv(const float* __restrict__ w_ext,
                                               const float* __restrict__ w_disp,
                                               unsigned short* __restrict__ WbF,
                                               unsigned short* __restrict__ WtapF){
  int d = blockIdx.x * 256 + threadIdx.x;
  if (blockIdx.x < 256){
    int j  = d & 7;
    int lane = (d >> 3) & 63;
    int mi = (d >> 9) & 3;
    int w  = (d >> 11) & 3;
    int ks = d >> 13;
    int m = w * 64 + mi * 16 + (lane & 15);
    int k = ks * 32 + (lane >> 4) * 8 + j;
    WbF[d] = f2bf(w_ext[m * 257 + 1 + k]);
  } else {
    int d2 = d - 65536;                 // 0..4095
    int j  = d2 & 7;
    int lane = (d2 >> 3) & 63;
    int ks = d2 >> 9;
    int tap = lane & 15;
    int k = ks * 32 + (lane >> 4) * 8 + j;
    WtapF[d2] = (tap < 9) ? f2bf(w_disp[k * 9 + tap]) : (unsigned short)0;
  }
}

// ---- KB: fused transpose-stage + GEMM, SINGLE-STAGE, ASM-pinned depth-32.
//   launch_bounds(256,2): 256-reg budget so the 64-VGPR in-flight set FITS
//   (R6's (256,3) forced a scratch spill that serialized the pipeline:
//   VGPR stuck at 84, +16MB spill writes).
//   U layout: U2[b][o>>2][p][o&3] — lane's 4 consecutive-o acc values pack
//   into one 8-B store; 16 lanes = 128 B contiguous. 64 store instrs/block.
typedef __attribute__((ext_vector_type(8))) short bf16x8;
typedef __attribute__((ext_vector_type(4))) short bf16x4;
typedef __attribute__((ext_vector_type(4))) float f32x4;

__global__ __launch_bounds__(256, 2) void kb_gemm(
    const float* __restrict__ x,             // [NB][NC][HW] fp32
    const unsigned short* __restrict__ Wb,   // fragment-major, 65536 shorts
    const unsigned short* __restrict__ Wtap, // fragment-major, 4096 shorts
    unsigned short* __restrict__ U,          // [NB][64][HW][4] bf16
    float* __restrict__ T)                   // [9][NP] fp32
{
  // [ks][unit][(n15 + kq*16)*8 + j] : 8 * 4 * 512 shorts = 32 KB
  __shared__ __align__(16) unsigned short smem[8 * 2048];
  int bx = blockIdx.x;            // 1920 = 16 b * 120 nt
  int b  = bx / 120;
  int nt = bx - b * 120;
  int p0 = nt * 64;               // hw offset within image (64 | 7680)

  int tid  = threadIdx.x;
  int lane = tid & 63;
  int w    = tid >> 6;            // wave 0..3 ; wm = w (m-quarter of 64)
  int l15 = lane & 15;
  int lq  = lane >> 4;

  // staging role: thread = (pixel pair q, 32-ch group cg)
  int q  = tid & 31;              // pixel pair: n = 2q, 2q+1
  int cg = tid >> 5;              // 0..7 : channels cg*32..cg*32+31 (= k-step)
  const float* xb_u = x + (size_t)b * NC * HW + p0;   // wave-uniform base
  uint32_t voff0 = ((uint32_t)cg * 32u * (uint32_t)HW + 2u * (uint32_t)q) * 4u;

  // ---- issue ALL 32 staging loads via asm (depth-32, pinned) --------------
  float2 v[32];
#define GL(i) asm volatile("global_load_dwordx2 %0, %1, %2"                   \
    : "=v"(v[i])                                                              \
    : "v"(voff0 + (uint32_t)((i) * HW * 4)), "s"(xb_u) : "memory")
  GL(0); GL(1); GL(2); GL(3); GL(4); GL(5); GL(6); GL(7);
  GL(8); GL(9); GL(10); GL(11); GL(12); GL(13); GL(14); GL(15);
  GL(16); GL(17); GL(18); GL(19); GL(20); GL(21); GL(22); GL(23);
  GL(24); GL(25); GL(26); GL(27); GL(28); GL(29); GL(30); GL(31);
#undef GL

  // A-prologue (ks=0): issued after x loads; 5 loads/wave (atA unconditional
  // so every wave carries exactly 5 — keeps vmcnt arithmetic wave-uniform).
  bf16x8 afA[4], afB[4];
  bf16x8 atA, atB = {0,0,0,0,0,0,0,0};
  #pragma unroll
  for (int mi = 0; mi < 4; ++mi)
    afA[mi] = *(const bf16x8*)(Wb + ((w * 4 + mi) << 9) + lane * 8);
  atA = *(const bf16x8*)(Wtap + lane * 8);

  f32x4 zero = {0.f, 0.f, 0.f, 0.f};
  f32x4 acc[4][4];
  f32x4 acct[4];
  #pragma unroll
  for (int mi = 0; mi < 4; ++mi){
    acct[mi] = zero;
    #pragma unroll
    for (int ni = 0; ni < 4; ++ni) acc[mi][ni] = zero;
  }

  // ---- counted drains + convert groups ------------------------------------
  int n0 = 2 * q;
  unsigned short* sw0 = smem + cg * 2048 + (n0 >> 4) * 512;
  int n15a = n0 & 15;
#define CVT_GROUP(g)                                                          \
  { unsigned short ha[8], hb[8];                                              \
    _Pragma("unroll")                                                         \
    for (int j = 0; j < 8; ++j){                                              \
      ha[j] = f2bf(v[8 * (g) + j].x);                                         \
      hb[j] = f2bf(v[8 * (g) + j].y);                                         \
    }                                                                         \
    *(bf16x8*)(sw0 + (n15a     + (g) * 16) * 8) = *(bf16x8*)ha;               \
    *(bf16x8*)(sw0 + (n15a + 1 + (g) * 16) * 8) = *(bf16x8*)hb;               \
  }

  asm volatile("s_waitcnt vmcnt(24)" ::: "memory");
  __builtin_amdgcn_sched_barrier(0);
  CVT_GROUP(0)
  asm volatile("s_waitcnt vmcnt(16)" ::: "memory");
  __builtin_amdgcn_sched_barrier(0);
  CVT_GROUP(1)
  asm volatile("s_waitcnt vmcnt(8)" ::: "memory");
  __builtin_amdgcn_sched_barrier(0);
  CVT_GROUP(2)
  asm volatile("s_waitcnt vmcnt(5)" ::: "memory");   // all x done; A stays in flight
  __builtin_amdgcn_sched_barrier(0);
  CVT_GROUP(3)
#undef CVT_GROUP

  asm volatile("s_waitcnt lgkmcnt(0)" ::: "memory"); // LDS writes visible
  __builtin_amdgcn_sched_barrier(0);
  __builtin_amdgcn_s_barrier();
  __builtin_amdgcn_sched_barrier(0);

  // ---- compute phase: 8 steps, no barriers, depth-1 A prefetch ------------
#define KB_STEP(T_, AFC, AFN, ATC, ATN)                                       \
  {                                                                           \
    constexpr int t_ = (T_);                                                  \
    if (t_ + 1 < 8) {                                                         \
      _Pragma("unroll")                                                       \
      for (int mi = 0; mi < 4; ++mi)                                          \
        AFN[mi] = *(const bf16x8*)(Wb + (((t_ + 1) * 16 + w * 4 + mi) << 9)   \
                                   + lane * 8);                               \
      if (w == 0)                                                             \
        ATN = *(const bf16x8*)(Wtap + ((t_ + 1) << 9) + lane * 8);            \
    }                                                                         \
    bf16x8 bg[4];                                                             \
    _Pragma("unroll")                                                         \
    for (int ni = 0; ni < 4; ++ni)                                            \
      bg[ni] = *(const bf16x8*)(smem + t_ * 2048 + ni * 512 + lane * 8);      \
    _Pragma("unroll")                                                         \
    for (int mi = 0; mi < 4; ++mi)                                            \
      _Pragma("unroll")                                                       \
      for (int ni = 0; ni < 4; ++ni)                                          \
        acc[mi][ni] = __builtin_amdgcn_mfma_f32_16x16x32_bf16(AFC[mi], bg[ni],\
                                                      acc[mi][ni], 0, 0, 0);  \
    if (w == 0) {                                                             \
      _Pragma("unroll")                                                       \
      for (int ni = 0; ni < 4; ++ni)                                          \
        acct[ni] = __builtin_amdgcn_mfma_f32_16x16x32_bf16(ATC, bg[ni],       \
                                                       acct[ni], 0, 0, 0);    \
    }                                                                         \
  }

  KB_STEP(0, afA, afB, atA, atB)
  KB_STEP(1, afB, afA, atB, atA)
  KB_STEP(2, afA, afB, atA, atB)
  KB_STEP(3, afB, afA, atB, atA)
  KB_STEP(4, afA, afB, atA, atB)
  KB_STEP(5, afB, afA, atB, atA)
  KB_STEP(6, afA, afB, atA, atB)
  KB_STEP(7, afB, afA, atB, atA)
#undef KB_STEP

  // epilogue U2[b][og][p][4]: lane packs 4 consecutive-o values into one
  // 8-B store; 16 lanes = consecutive px = 128 B contiguous.
  #pragma unroll
  for (int mi = 0; mi < 4; ++mi){
    int og = w * 16 + mi * 4 + lq;          // o >> 2
    #pragma unroll
    for (int ni = 0; ni < 4; ++ni){
      int n = ni * 16 + l15;
      unsigned short h[4];
      #pragma unroll
      for (int r = 0; r < 4; ++r) h[r] = f2bf(acc[mi][ni][r]);
      *(bf16x4*)(U + (((size_t)b * 64 + og) * HW + p0 + n) * 4) = *(bf16x4*)h;
    }
  }
  // epilogue T (wave 0): row = lq*4+r = tap index, keep rows 0..8
  if (w == 0){
    #pragma unroll
    for (int ni = 0; ni < 4; ++ni){
      int n = ni * 16 + l15;
      #pragma unroll
      for (int r = 0; r < 4; ++r){
        int k = lq * 4 + r;
        if (k < 9)
          T[(size_t)k * NP + (size_t)b * HW + p0 + n] = acct[ni][r];
      }
    }
  }
}

// ---- KP: per-pixel grid params (wy, dlerp, off0, off1) ----------------------
__global__ __launch_bounds__(256) void kp_grid(
    const float* __restrict__ P2, const float* __restrict__ b_disp,
    const float* __restrict__ T, float4* __restrict__ pre)
{
  int p = blockIdx.x * 256 + threadIdx.x;   // 0..122879
  int b  = p / HW;
  int hw = p - b * HW;
  int y  = hw / NW;
  int xx = hw - y * NW;

  float d = 0.f;
  #pragma unroll
  for (int ky = 0; ky < 3; ++ky){
    int yy2 = y + ky - 1;
    if (yy2 < 0 || yy2 >= NH) continue;
    #pragma unroll
    for (int kx = 0; kx < 3; ++kx){
      int xx2 = xx + kx - 1;
      if (xx2 < 0 || xx2 >= NW) continue;
      d += T[(size_t)(ky * 3 + kx) * NP + b * HW + yy2 * NW + xx2];
    }
  }
  float th = tanhf(d + b_disp[0]);

  float fy = P2[b * 12 + 5] * 0.0625f;
  float cy = P2[b * 12 + 6] * 0.0625f;
  float Ty = P2[b * 12 + 7] * 0.0625f;

  float ysb   = fmaxf(1.535f * ((float)y - cy) / 1.765f, 0.f) * (1.f / 24.f);
  float ybase = -1.f + (float)y * (2.f / 47.f);
  float gy = ybase + ysb + 0.1f * th;
  float iy = fminf(fmaxf((gy + 1.f) * 0.5f * 47.f, 0.f), 47.f);
  float fiy0 = floorf(iy);
  float wy = iy - fiy0;
  int iy0 = (int)fiy0;
  int iy1 = min(iy0 + 1, 47);

  float inv_den = 1.f / (fabsf(fy * 1.65f + Ty) + 1e-10f);
  float dr0 = fmaxf(fy * 0.54f * ((float)iy0 - cy) * inv_den, 0.f);
  float dr1 = fmaxf(fy * 0.54f * ((float)iy1 - cy) * inv_den, 0.f);
  float dlerp = (1.f - wy) * dr0 + wy * dr1;

  float4 pr;
  pr.x = wy; pr.y = dlerp;
  pr.z = __int_as_float(iy0 * NW + xx);
  pr.w = __int_as_float(iy1 * NW + xx);
  pre[p] = pr;
}

// ---- KC: lerp + matvec-residual ReLU; U2 rows read as 8-B coalesced --------
__global__ __launch_bounds__(256) void kc_epilogue(
    const float* __restrict__ x, const float* __restrict__ w_ext,
    const float* __restrict__ b_ext, const float* __restrict__ alpha,
    const unsigned short* __restrict__ U, const float4* __restrict__ pre,
    float* __restrict__ out)
{
  int bx = blockIdx.x;            // 3840 = 480 ptile * 8 cg
  int ptile = bx >> 3;
  int cg    = bx & 7;
  int p = ptile * 256 + threadIdx.x;
  int b  = p / HW;
  int hw = p - b * HW;

  float4 pr = pre[p];
  float wy    = pr.x;
  float dlerp = pr.y;
  int off0 = __float_as_int(pr.z);
  int off1 = __float_as_int(pr.w);
  float w1 = 1.f - wy;
  float al = alpha[0];

  int og0 = cg * 8;               // o block: o = og*4 + r
  const unsigned short* Ua = U + (((size_t)b * 64 + og0) * HW) * 4;
  bf16x4 ua[8], ub[8];
  #pragma unroll
  for (int i = 0; i < 8; ++i){
    ua[i] = *(const bf16x4*)(Ua + ((size_t)i * HW + off0) * 4);
    ub[i] = *(const bf16x4*)(Ua + ((size_t)i * HW + off1) * 4);
  }

  size_t base0 = (size_t)(b * NC) * HW;
  const float* xb = x + base0 + hw;
  float* ob = out + base0 + hw;

  int o0 = cg * 32;
  #pragma unroll
  for (int i = 0; i < 8; ++i){
    #pragma unroll
    for (int r = 0; r < 4; ++r){
      int o = o0 + i * 4 + r;
      float u0 = bf2f((unsigned short)ua[i][r]);
      float u1 = bf2f((unsigned short)ub[i][r]);
      float val = w1 * u0 + wy * u1 + w_ext[o * 257] * dlerp + b_ext[o];
      float rr = xb[(size_t)o * HW] + al * val;
      ob[(size_t)o * HW] = fmaxf(rr, 0.f);
    }
  }
}

// ---------------------------------------------------------------------------
extern "C" void kernel_launch(void* const* d_in, const int* in_sizes, int n_in,
                              void* d_out, int out_size, void* d_ws, size_t ws_size,
                              hipStream_t stream) {
  const float* features = (const float*)d_in[0];
  const float* P2       = (const float*)d_in[1];
  const float* w_disp   = (const float*)d_in[2];
  const float* b_disp   = (const float*)d_in[3];
  const float* w_ext    = (const float*)d_in[4];
  const float* b_ext    = (const float*)d_in[5];
  const float* alpha    = (const float*)d_in[6];
  float* out = (float*)d_out;

  char* ws = (char*)d_ws;
  const size_t U_bytes   = (size_t)NP * 256 * 2;    // 62,914,560
  const size_t T_bytes   = (size_t)9 * NP * 4;      //  4,423,680
  const size_t pre_bytes = (size_t)NP * 16;         //  1,966,080
  unsigned short* U    = (unsigned short*)ws;
  float*          T    = (float*)(ws + U_bytes);
  float4*         pre  = (float4*)(ws + U_bytes + T_bytes);
  unsigned short* Wb   = (unsigned short*)(ws + U_bytes + T_bytes + pre_bytes);
  unsigned short* Wtap = Wb + 256 * 256;

  hipLaunchKernelGGL(kw_conv,     dim3(272),  dim3(256), 0, stream, w_ext, w_disp, Wb, Wtap);
  hipLaunchKernelGGL(kb_gemm,     dim3(1920), dim3(256), 0, stream, features, Wb, Wtap, U, T);
  hipLaunchKernelGGL(kp_grid,     dim3(480),  dim3(256), 0, stream, P2, b_disp, T, pre);
  hipLaunchKernelGGL(kc_epilogue, dim3(3840), dim3(256), 0, stream,
                     features, w_ext, b_ext, alpha, U, pre, out);
}